// Round 1
// baseline (339.704 us; speedup 1.0000x reference)
//
#include <hip/hip_runtime.h>

// DiffKS: x = invert_lpc(y, A_exc)  [order-6 time-varying FIR]
//         out = sample_wise_lpc(x, A_loop)  [order-2 time-varying IIR]
// B=48, T=88200, N_EXC=6, N_LOOP=2, all fp32.
//
// Parallelization of the IIR: |a1|,|a2| <= 0.25 so ||M_t*M_{t-1}||_inf <= 0.5
// (companion matrices). State perturbations decay by >=0.5 every 2 steps ->
// a chunk started from zero state converges to the true trajectory within
// 0.5^24 ~ 6e-8 after 48 warm-up samples. So: one thread per 256-sample
// chunk, 48-sample zero-state warm-up, no cross-chunk communication.

#define T_LEN 88200
#define B_N   48
#define CCH   256   // chunk length (multiple of 4)
#define WUP   48    // warm-up samples (multiple of 4)
#define NCH   345   // ceil(T_LEN / CCH)

struct Grp {
    float4 ae0, ae1, ae2, ae3, ae4, ae5; // A_exc[g..g+3][0..5] (24 floats)
    float4 al0, al1;                     // A_loop[g..g+3][0..1] (8 floats)
    float4 yv;                           // y[g..g+3]
};

__device__ __forceinline__ Grp load_grp(const float* __restrict__ yb,
                                        const float* __restrict__ aeb,
                                        const float* __restrict__ alb,
                                        int g) {
    Grp r;
    const float4* ae = (const float4*)(aeb + (size_t)g * 6);
    r.ae0 = ae[0]; r.ae1 = ae[1]; r.ae2 = ae[2];
    r.ae3 = ae[3]; r.ae4 = ae[4]; r.ae5 = ae[5];
    const float4* al = (const float4*)(alb + (size_t)g * 2);
    r.al0 = al[0]; r.al1 = al[1];
    r.yv = *(const float4*)(yb + g);
    return r;
}

// Computes 4 samples: FIR from the 12-float rolling y-window, then the
// order-2 IIR update. Shifts the window by 4.
__device__ __forceinline__ void compute_grp(const Grp& G, float* yw,
                                            float& y1, float& y2, float4& o) {
    yw[8] = G.yv.x; yw[9] = G.yv.y; yw[10] = G.yv.z; yw[11] = G.yv.w;
    const float* aef = (const float*)&G.ae0; // 24 contiguous floats
    const float* alf = (const float*)&G.al0; // 8 contiguous floats
    float ov[4];
#pragma unroll
    for (int j = 0; j < 4; ++j) {
        float xv = yw[8 + j];
#pragma unroll
        for (int k = 1; k <= 6; ++k)
            xv = fmaf(aef[j * 6 + (k - 1)], yw[8 + j - k], xv);
        float yt = fmaf(-alf[j * 2 + 1], y2, fmaf(-alf[j * 2], y1, xv));
        y2 = y1; y1 = yt;
        ov[j] = yt;
    }
    o = make_float4(ov[0], ov[1], ov[2], ov[3]);
#pragma unroll
    for (int j = 0; j < 8; ++j) yw[j] = yw[j + 4];
}

__global__ __launch_bounds__(256) void diffks_kernel(
    const float* __restrict__ y, const float* __restrict__ A_exc,
    const float* __restrict__ A_loop, float* __restrict__ out) {
    int idx = blockIdx.x * blockDim.x + threadIdx.x;
    if (idx >= B_N * NCH) return;
    int b = idx / NCH;
    int c = idx - b * NCH;
    int s = c * CCH;
    int e = min(s + CCH, T_LEN);
    int g0 = (s >= WUP) ? (s - WUP) : 0;

    const float* yb  = y      + (size_t)b * T_LEN;
    const float* aeb = A_exc  + (size_t)b * T_LEN * 6;
    const float* alb = A_loop + (size_t)b * T_LEN * 2;
    float*       ob  = out    + (size_t)b * T_LEN;

    float yw[12];
    if (g0 >= 8) {
        float4 m2 = *(const float4*)(yb + g0 - 8);
        float4 m1 = *(const float4*)(yb + g0 - 4);
        yw[0] = m2.x; yw[1] = m2.y; yw[2] = m2.z; yw[3] = m2.w;
        yw[4] = m1.x; yw[5] = m1.y; yw[6] = m1.z; yw[7] = m1.w;
    } else { // only chunk 0: zero initial history
#pragma unroll
        for (int j = 0; j < 8; ++j) yw[j] = 0.f;
    }
    float y1 = 0.f, y2 = 0.f; // zero-state warm-up start

    // 2-deep software prefetch pipeline over 4-sample groups.
    Grp A = load_grp(yb, aeb, alb, g0);
    Grp Bu;
    if (g0 + 4 < e) Bu = load_grp(yb, aeb, alb, g0 + 4);
    int g = g0;
    while (true) {
        Grp Cn, Dn;
        if (g + 8 < e) Cn = load_grp(yb, aeb, alb, g + 8);
        float4 o;
        compute_grp(A, yw, y1, y2, o);
        if (g >= s) *(float4*)(ob + g) = o;
        g += 4;
        if (g >= e) break;
        if (g + 8 < e) Dn = load_grp(yb, aeb, alb, g + 8);
        compute_grp(Bu, yw, y1, y2, o);
        if (g >= s) *(float4*)(ob + g) = o;
        g += 4;
        if (g >= e) break;
        A = Cn; Bu = Dn;
    }
}

extern "C" void kernel_launch(void* const* d_in, const int* in_sizes, int n_in,
                              void* d_out, int out_size, void* d_ws, size_t ws_size,
                              hipStream_t stream) {
    const float* y      = (const float*)d_in[0];
    const float* A_exc  = (const float*)d_in[1];
    const float* A_loop = (const float*)d_in[2];
    float* out = (float*)d_out;

    const int total = B_N * NCH; // 16560 threads
    const int block = 256;
    const int grid = (total + block - 1) / block; // 65
    diffks_kernel<<<grid, block, 0, stream>>>(y, A_exc, A_loop, out);
}

// Round 2
// 202.736 us; speedup vs baseline: 1.6756x; 1.6756x over previous
//
#include <hip/hip_runtime.h>

// DiffKS: x = invert_lpc(y, A_exc)  [order-6 time-varying FIR]
//         out = sample_wise_lpc(x, A_loop)  [order-2 time-varying IIR]
// B=48, T=88200, fp32.
//
// R2 design: one WAVE per 256-sample chunk (16560 waves total).
//  - 64-sample zero-state warm-up (|a|<=0.25 -> perturbation decay 0.5 per
//    2 steps -> 0.5^32 ~ 2e-10, far below threshold).
//  - Stage the 320-sample window (y, A_exc, A_loop) into LDS with coalesced
//    float4 loads.
//  - Each lane computes 5 samples: FIR x_t, then composes the 5 affine IIR
//    steps s_t = M_t s + b_t into one (P, c) [2x2 + 2-vec].
//  - Hillis-Steele inclusive scan of (P,c) across 64 lanes (6 shfl_up steps).
//  - Exclusive prefix c from lane-1 = incoming state; replay 5 samples.
//  - Outputs routed through LDS for coalesced float4 stores.

#define T_LEN 88200
#define B_N   48
#define CCH   256
#define WUP   64
#define WIN   320            // CCH + WUP
#define NCH   345            // ceil(T_LEN / CCH)
#define WPB   4              // waves per block
#define YSH   328            // y window floats: [w0-8, w0+320)
#define AESH  1920           // WIN*6
#define ALSH  640            // WIN*2
#define SLOT  (YSH + AESH + ALSH)  // 2888 floats = 11552 B; x4 = 46208 B/block

__global__ __launch_bounds__(256) void diffks_kernel(
    const float* __restrict__ y, const float* __restrict__ A_exc,
    const float* __restrict__ A_loop, float* __restrict__ out) {
    __shared__ float lds[WPB * SLOT];
    const int tid  = threadIdx.x;
    const int widx = tid >> 6;
    const int lane = tid & 63;
    float* sh    = lds + widx * SLOT;
    float* sh_y  = sh;                 // sh_y[i] = y[w0-8+i]
    float* sh_ae = sh + YSH;           // [li*6 + k]
    float* sh_al = sh + YSH + AESH;    // [li*2 + k]; reused as output buffer

    const int w  = blockIdx.x * WPB + widx;   // 0..16559 (grid is exact)
    const int b  = w / NCH;
    const int c  = w - b * NCH;
    const int s  = c * CCH;
    const int w0 = s - WUP;

    const float* yb  = y      + (size_t)b * T_LEN;
    const float* aeb = A_exc  + (size_t)b * T_LEN * 6;
    const float* alb = A_loop + (size_t)b * T_LEN * 2;
    float*       ob  = out    + (size_t)b * T_LEN;

    // ---- stage window into LDS (coalesced fast path for interior chunks) ----
    if (c != 0 && c != NCH - 1) {
        const float4* gy = (const float4*)(yb + w0 - 8);       // 16B aligned
        for (int i = lane; i < YSH / 4; i += 64) ((float4*)sh_y)[i] = gy[i];
        const float4* ga = (const float4*)(aeb + (size_t)w0 * 6);
        for (int i = lane; i < AESH / 4; i += 64) ((float4*)sh_ae)[i] = ga[i];
        const float4* gl = (const float4*)(alb + (size_t)w0 * 2);
        for (int i = lane; i < ALSH / 4; i += 64) ((float4*)sh_al)[i] = gl[i];
    } else {
        const float* pae = aeb + (long)w0 * 6;
        const float* pal = alb + (long)w0 * 2;
        for (int i = lane; i < YSH; i += 64) {
            int t = w0 - 8 + i;
            sh_y[i] = (t >= 0 && t < T_LEN) ? yb[t] : 0.f;
        }
        for (int i = lane; i < AESH; i += 64) {
            int t = w0 + i / 6;
            sh_ae[i] = (t >= 0 && t < T_LEN) ? pae[i] : 0.f;
        }
        for (int i = lane; i < ALSH; i += 64) {
            int t = w0 + i / 2;
            sh_al[i] = (t >= 0 && t < T_LEN) ? pal[i] : 0.f;
        }
    }
    __syncthreads();

    // ---- per-lane: FIR + local affine composition over 5 samples ----
    float xs[5], a1s[5], a2s[5];
    float p00 = 1.f, p01 = 0.f, p10 = 0.f, p11 = 1.f, c0 = 0.f, c1 = 0.f;
    const int base = 5 * lane;          // local sample index in [0, 320)
#pragma unroll
    for (int j = 0; j < 5; ++j) {
        const int li = base + j;
        float xv = sh_y[li + 8];
#pragma unroll
        for (int k = 1; k <= 6; ++k)
            xv = fmaf(sh_ae[li * 6 + (k - 1)], sh_y[li + 8 - k], xv);
        xs[j] = xv;
        const float a1 = sh_al[li * 2], a2 = sh_al[li * 2 + 1];
        a1s[j] = a1; a2s[j] = a2;
        // P <- M_t * P ; c <- M_t * c + b_t   (M_t = [[-a1,-a2],[1,0]])
        const float n00 = fmaf(-a1, p00, -a2 * p10);
        const float n01 = fmaf(-a1, p01, -a2 * p11);
        p10 = p00; p11 = p01; p00 = n00; p01 = n01;
        const float nc0 = fmaf(-a1, c0, fmaf(-a2, c1, xv));
        c1 = c0; c0 = nc0;
    }

    // ---- inclusive scan of affine maps across the wave ----
    for (int d = 1; d < 64; d <<= 1) {
        const float q00 = __shfl_up(p00, d, 64), q01 = __shfl_up(p01, d, 64);
        const float q10 = __shfl_up(p10, d, 64), q11 = __shfl_up(p11, d, 64);
        const float qc0 = __shfl_up(c0, d, 64),  qc1 = __shfl_up(c1, d, 64);
        if (lane >= d) {
            const float m00 = fmaf(p00, q00, p01 * q10);
            const float m01 = fmaf(p00, q01, p01 * q11);
            const float m10 = fmaf(p10, q00, p11 * q10);
            const float m11 = fmaf(p10, q01, p11 * q11);
            const float nc0 = fmaf(p00, qc0, fmaf(p01, qc1, c0));
            const float nc1 = fmaf(p10, qc0, fmaf(p11, qc1, c1));
            p00 = m00; p01 = m01; p10 = m10; p11 = m11; c0 = nc0; c1 = nc1;
        }
    }
    // exclusive prefix: state entering this lane's block (zero initial state)
    float y1 = __shfl_up(c0, 1, 64);
    float y2 = __shfl_up(c1, 1, 64);
    if (lane == 0) { y1 = 0.f; y2 = 0.f; }

    // ---- replay 5 samples, stage results to LDS (reuse sh_al) ----
    __syncthreads();   // all sh_al coefficient reads are done (held in regs)
#pragma unroll
    for (int j = 0; j < 5; ++j) {
        const float yt = fmaf(-a1s[j], y1, fmaf(-a2s[j], y2, xs[j]));
        y2 = y1; y1 = yt;
        sh_al[base + j] = yt;
    }
    __syncthreads();

    // ---- coalesced float4 store of the 256 output samples ----
    const int t4 = s + 4 * lane;
    if (t4 < T_LEN) {   // tail chunk: T_LEN - s is a multiple of 4
        const float4 o = ((const float4*)(sh_al + WUP))[lane];
        *(float4*)(ob + t4) = o;
    }
}

extern "C" void kernel_launch(void* const* d_in, const int* in_sizes, int n_in,
                              void* d_out, int out_size, void* d_ws, size_t ws_size,
                              hipStream_t stream) {
    const float* y      = (const float*)d_in[0];
    const float* A_exc  = (const float*)d_in[1];
    const float* A_loop = (const float*)d_in[2];
    float* out = (float*)d_out;

    const int chunks = B_N * NCH;            // 16560 = 4140 * 4 exactly
    const int grid   = chunks / WPB;         // 4140 blocks, 256 thr = 4 waves
    diffks_kernel<<<grid, 256, 0, stream>>>(y, A_exc, A_loop, out);
}

// Round 3
// 190.103 us; speedup vs baseline: 1.7869x; 1.0665x over previous
//
#include <hip/hip_runtime.h>

// DiffKS: x = invert_lpc(y, A_exc)  [order-6 time-varying FIR]
//         out = sample_wise_lpc(x, A_loop)  [order-2 time-varying IIR]
// B=48, T=88200, fp32.
//
// R3 design: LDS-free, one wave per 224-output-sample chunk.
//  - 4 samples/lane -> per-lane A_exc slice = 96 B (16B-aligned float4 x6),
//    A_loop slice = 32 B (float4 x2), y slice = 16 B: ALL direct global
//    loads, no LDS staging, no barrier. Adjacent lanes tile memory
//    contiguously -> no cache-line waste.
//  - y history (6 taps) via 2x __shfl_up of the lane's float4 (lanes 0/1
//    load their halo directly, guarded).
//  - 32-sample zero-state warm-up (lanes 0..7). |a|<=0.25 -> companion
//    2-step contraction 0.5 -> truncation error ~0.5^16*|y| ~ 3e-4.
//  - Per-lane affine compose (4 IIR steps), wave scan TRUNCATED to rounds
//    d=1,2,4 (full 2x2+vec) + d=8 (c only): P over 32 steps has norm
//    <=1.5e-5, so d>=16 rounds contribute <1e-9. 22 shuffles total.
//  - Direct coalesced float4 stores from registers (lanes 8..63).

#define T_LEN 88200
#define B_N   48
#define OUT_W 224          // output samples per wave
#define WUP   32           // warm-up samples (lanes 0..7)
#define NCH   394          // ceil(T_LEN / OUT_W)
#define WPB   4            // waves per block (block = 256)

__device__ __forceinline__ float4 zero4() { return make_float4(0.f, 0.f, 0.f, 0.f); }

__device__ __forceinline__ float4 ld_guard(const float* p, int t) {
    // whole-float4 guard: callers guarantee t % 4 == 0
    if (t >= 0 && t + 3 < T_LEN) return *(const float4*)(p + t);
    return zero4();
}

__global__ __launch_bounds__(256, 5) void diffks_kernel(
    const float* __restrict__ y, const float* __restrict__ A_exc,
    const float* __restrict__ A_loop, float* __restrict__ out) {
    const int tid  = threadIdx.x;
    const int widx = tid >> 6;
    const int lane = tid & 63;
    const int w = blockIdx.x * WPB + widx;      // 0..18911 (grid exact)
    const int b = w / NCH;
    const int c = w - b * NCH;
    const int s  = c * OUT_W;
    const int w0 = s - WUP;
    const int t0 = w0 + 4 * lane;               // this lane's first sample

    const float* yb  = y      + (size_t)b * T_LEN;
    const float* aeb = A_exc  + (size_t)b * T_LEN * 6;
    const float* alb = A_loop + (size_t)b * T_LEN * 2;
    float*       ob  = out    + (size_t)b * T_LEN;

    // ---- per-lane direct loads (all 16B-aligned) ----
    const bool valid = (t0 >= 0) && (t0 + 3 < T_LEN);
    float4 yv, ae0, ae1, ae2, ae3, ae4, ae5, al0, al1;
    if (valid) {
        yv = *(const float4*)(yb + t0);
        const float4* pae = (const float4*)(aeb + (size_t)t0 * 6);
        ae0 = pae[0]; ae1 = pae[1]; ae2 = pae[2];
        ae3 = pae[3]; ae4 = pae[4]; ae5 = pae[5];
        const float4* pal = (const float4*)(alb + (size_t)t0 * 2);
        al0 = pal[0]; al1 = pal[1];
    } else {
        yv = ae0 = ae1 = ae2 = ae3 = ae4 = ae5 = al0 = al1 = zero4();
    }

    // ---- y history via shuffles (lanes 0/1 load halo) ----
    float4 ymid, ylo;
    ymid.x = __shfl_up(yv.x, 1, 64); ymid.y = __shfl_up(yv.y, 1, 64);
    ymid.z = __shfl_up(yv.z, 1, 64); ymid.w = __shfl_up(yv.w, 1, 64);
    ylo.x  = __shfl_up(yv.x, 2, 64); ylo.y  = __shfl_up(yv.y, 2, 64);
    ylo.z  = __shfl_up(yv.z, 2, 64); ylo.w  = __shfl_up(yv.w, 2, 64);
    if (lane == 0) ymid = ld_guard(yb, t0 - 4);
    if (lane <= 1) ylo  = ld_guard(yb, t0 - 8);

    float yw[12] = { ylo.x, ylo.y, ylo.z, ylo.w,
                     ymid.x, ymid.y, ymid.z, ymid.w,
                     yv.x, yv.y, yv.z, yv.w };        // yw[i] = y[t0-8+i]
    float aef[24] = { ae0.x, ae0.y, ae0.z, ae0.w, ae1.x, ae1.y, ae1.z, ae1.w,
                      ae2.x, ae2.y, ae2.z, ae2.w, ae3.x, ae3.y, ae3.z, ae3.w,
                      ae4.x, ae4.y, ae4.z, ae4.w, ae5.x, ae5.y, ae5.z, ae5.w };
    float alf[8]  = { al0.x, al0.y, al0.z, al0.w, al1.x, al1.y, al1.z, al1.w };

    // ---- FIR + local affine composition over 4 samples ----
    float xs[4], a1s[4], a2s[4];
    float p00 = 1.f, p01 = 0.f, p10 = 0.f, p11 = 1.f, c0 = 0.f, c1 = 0.f;
#pragma unroll
    for (int j = 0; j < 4; ++j) {
        float xv = yw[8 + j];
#pragma unroll
        for (int k = 1; k <= 6; ++k)
            xv = fmaf(aef[j * 6 + (k - 1)], yw[8 + j - k], xv);
        xs[j] = xv;
        const float a1 = alf[j * 2], a2 = alf[j * 2 + 1];
        a1s[j] = a1; a2s[j] = a2;
        // P <- M_t * P ; c <- M_t * c + b_t   (M_t = [[-a1,-a2],[1,0]])
        const float n00 = fmaf(-a1, p00, -a2 * p10);
        const float n01 = fmaf(-a1, p01, -a2 * p11);
        p10 = p00; p11 = p01; p00 = n00; p01 = n01;
        const float nc0 = fmaf(-a1, c0, fmaf(-a2, c1, xv));
        c1 = c0; c0 = nc0;
    }

    // ---- truncated wave scan: d=1,2,4 full; d=8 c-only ----
#pragma unroll
    for (int d = 1; d <= 4; d <<= 1) {
        const float q00 = __shfl_up(p00, d, 64), q01 = __shfl_up(p01, d, 64);
        const float q10 = __shfl_up(p10, d, 64), q11 = __shfl_up(p11, d, 64);
        const float qc0 = __shfl_up(c0, d, 64),  qc1 = __shfl_up(c1, d, 64);
        if (lane >= d) {
            const float m00 = fmaf(p00, q00, p01 * q10);
            const float m01 = fmaf(p00, q01, p01 * q11);
            const float m10 = fmaf(p10, q00, p11 * q10);
            const float m11 = fmaf(p10, q01, p11 * q11);
            const float nc0 = fmaf(p00, qc0, fmaf(p01, qc1, c0));
            const float nc1 = fmaf(p10, qc0, fmaf(p11, qc1, c1));
            p00 = m00; p01 = m01; p10 = m10; p11 = m11; c0 = nc0; c1 = nc1;
        }
    }
    {   // d = 8: P spans <=32 steps (norm <=1.5e-5) -> only c matters
        const float qc0 = __shfl_up(c0, 8, 64), qc1 = __shfl_up(c1, 8, 64);
        if (lane >= 8) {
            const float nc0 = fmaf(p00, qc0, fmaf(p01, qc1, c0));
            const float nc1 = fmaf(p10, qc0, fmaf(p11, qc1, c1));
            c0 = nc0; c1 = nc1;
        }
    }

    // ---- exclusive prefix = incoming state; replay 4 samples ----
    float y1 = __shfl_up(c0, 1, 64);
    float y2 = __shfl_up(c1, 1, 64);
    if (lane == 0) { y1 = 0.f; y2 = 0.f; }
    float ov[4];
#pragma unroll
    for (int j = 0; j < 4; ++j) {
        const float yt = fmaf(-a1s[j], y1, fmaf(-a2s[j], y2, xs[j]));
        y2 = y1; y1 = yt;
        ov[j] = yt;
    }

    // ---- direct coalesced store (lanes 8..63 = output region) ----
    if (lane >= 8 && t0 < T_LEN)
        *(float4*)(ob + t0) = make_float4(ov[0], ov[1], ov[2], ov[3]);
}

extern "C" void kernel_launch(void* const* d_in, const int* in_sizes, int n_in,
                              void* d_out, int out_size, void* d_ws, size_t ws_size,
                              hipStream_t stream) {
    const float* y      = (const float*)d_in[0];
    const float* A_exc  = (const float*)d_in[1];
    const float* A_loop = (const float*)d_in[2];
    float* out = (float*)d_out;

    const int waves = B_N * NCH;          // 48 * 394 = 18912
    const int grid  = waves / WPB;        // 4728 blocks of 4 waves
    diffks_kernel<<<grid, 256, 0, stream>>>(y, A_exc, A_loop, out);
}